// Round 3
// baseline (622.785 us; speedup 1.0000x reference)
//
#include <hip/hip_runtime.h>
#include <math.h>

#define N_REFLNS 2000000
#define N_IMAGES 8192
#define N_RAC    1000000
#define MC       8
#define D_META   16
#define HIDDEN   32
#define LOG_2PI  1.8378770664093453f

// Workspace layout (bytes):
//   [0, 32768)          img_sum   (8192 f32)
//   [32768, 65536)      img_cnt   (8192 f32)
//   [65536, 65540)      kl_sum    (1 f32)
//   [65664, 65664+32e6) zT        (N_RAC x MC f32, transposed z for 32B gathers)

__device__ __forceinline__ float softplus_f(float x) {
    return fmaxf(x, 0.0f) + log1pf(expf(-fabsf(x)));
}

// ---------------- Kernel A: zT + KL, 4 RAC entries per thread ----------------
__global__ __launch_bounds__(256) void k_z_kl(
    const float* __restrict__ q_loc,
    const float* __restrict__ q_log_scale,
    const float* __restrict__ eps,
    float* __restrict__ zT,          // may be null (fallback)
    float* __restrict__ kl_sum)
{
    int t = blockIdx.x * 256 + threadIdx.x;
    int r0 = t * 4;
    float kl = 0.0f;
    if (r0 < N_RAC) {
        float4 ql  = *(const float4*)(q_loc + r0);
        float4 qls = *(const float4*)(q_log_scale + r0);
        float4 qs;
        qs.x = expf(qls.x); qs.y = expf(qls.y);
        qs.z = expf(qls.z); qs.w = expf(qls.w);
        kl = 0.5f * (qs.x * qs.x + ql.x * ql.x - 1.0f) - qls.x
           + 0.5f * (qs.y * qs.y + ql.y * ql.y - 1.0f) - qls.y
           + 0.5f * (qs.z * qs.z + ql.z * ql.z - 1.0f) - qls.z
           + 0.5f * (qs.w * qs.w + ql.w * ql.w - 1.0f) - qls.w;
        if (zT) {
            float zr[4][MC];
            #pragma unroll
            for (int s = 0; s < MC; s++) {
                float4 e = *(const float4*)(eps + (size_t)s * N_RAC + r0);
                zr[0][s] = ql.x + qs.x * e.x;
                zr[1][s] = ql.y + qs.y * e.y;
                zr[2][s] = ql.z + qs.z * e.z;
                zr[3][s] = ql.w + qs.w * e.w;
            }
            #pragma unroll
            for (int r = 0; r < 4; r++) {
                float4* dst = (float4*)(zT + (size_t)(r0 + r) * MC);
                dst[0] = make_float4(zr[r][0], zr[r][1], zr[r][2], zr[r][3]);
                dst[1] = make_float4(zr[r][4], zr[r][5], zr[r][6], zr[r][7]);
            }
        }
    }
    __shared__ float sred[256];
    sred[threadIdx.x] = kl;
    __syncthreads();
    #pragma unroll
    for (int s = 128; s > 0; s >>= 1) {
        if (threadIdx.x < s) sred[threadIdx.x] += sred[threadIdx.x + s];
        __syncthreads();
    }
    if (threadIdx.x == 0) atomicAdd(kl_sum, sred[0]);
}

// ---------------- Kernel B: MLP + likelihood, 1 reflection per thread --------
// Weights are read DIRECTLY from global memory with wave-uniform addresses in
// fully unrolled loops: the compiler promotes them to s_load_* (scalar pipe,
// free broadcast). No LDS staging, no per-thread weight arrays -> low VGPR.
template <bool HAS_Z>
__global__ __launch_bounds__(256) void k_main(
    const float* __restrict__ metadata,
    const float* __restrict__ W1, const float* __restrict__ b1,
    const float* __restrict__ W2, const float* __restrict__ b2,
    const float* __restrict__ iobs, const float* __restrict__ sigiobs,
    const int* __restrict__ image_id, const int* __restrict__ miller_id,
    const float* __restrict__ zT,
    const float* __restrict__ q_loc, const float* __restrict__ q_log_scale,
    const float* __restrict__ eps,
    float* __restrict__ out_ipred,
    float* __restrict__ img_sum, float* __restrict__ img_cnt)
{
    __shared__ int   s_id[256];
    __shared__ float s_ll[256];
    __shared__ float s_ct[256];

    int tid = threadIdx.x;
    int n = blockIdx.x * 256 + tid;
    bool valid = (n < N_REFLNS);
    float ll_sum = 0.0f;
    int img = -1;

    if (valid) {
        // issue scattered/per-thread loads early so they overlap the MLP
        int m = miller_id[n];
        float io = iobs[n];
        float sg = sigiobs[n];
        img = image_id[n];

        const float4* mrow = (const float4*)(metadata + (size_t)n * D_META);
        float4 m0 = mrow[0], m1 = mrow[1], m2 = mrow[2], m3 = mrow[3];
        float meta[D_META] = {m0.x, m0.y, m0.z, m0.w,
                              m1.x, m1.y, m1.z, m1.w,
                              m2.x, m2.y, m2.z, m2.w,
                              m3.x, m3.y, m3.z, m3.w};

        float f[MC];
        if (HAS_Z) {
            const float4* zp = (const float4*)(zT + (size_t)m * MC);
            float4 z0 = zp[0], z1 = zp[1];
            f[0] = z0.x; f[1] = z0.y; f[2] = z0.z; f[3] = z0.w;
            f[4] = z1.x; f[5] = z1.y; f[6] = z1.z; f[7] = z1.w;
        } else {
            float qlv = q_loc[m];
            float qsv = expf(q_log_scale[m]);
            #pragma unroll
            for (int s = 0; s < MC; s++) f[s] = qlv + qsv * eps[(size_t)s * N_RAC + m];
        }

        float acc[MC];
        #pragma unroll
        for (int s = 0; s < MC; s++) acc[s] = b2[s];          // s_load
        #pragma unroll
        for (int j = 0; j < HIDDEN; j++) {
            float hj = b1[j];                                  // s_load
            #pragma unroll
            for (int d = 0; d < D_META; d++)
                hj = fmaf(meta[d], W1[d * HIDDEN + j], hj);    // s_load (uniform)
            hj = fmaxf(hj, 0.0f);
            #pragma unroll
            for (int s = 0; s < MC; s++)
                acc[s] = fmaf(hj, W2[j * MC + s], acc[s]);     // s_load (uniform)
        }

        float inv_sg = 1.0f / sg;
        float sum_ip = 0.0f, sum_r2 = 0.0f;
        #pragma unroll
        for (int s = 0; s < MC; s++) {
            float sc = softplus_f(acc[s]);
            float ip = f[s] * f[s] * sc;
            sum_ip += ip;
            float r = (ip - io) * inv_sg;
            sum_r2 = fmaf(r, r, sum_r2);
        }
        out_ipred[n] = sum_ip * (1.0f / MC);
        ll_sum = -0.5f * sum_r2 - (float)MC * (logf(sg) + 0.5f * LOG_2PI);
    }

    // Segmented inclusive scan over sorted image ids (Hillis-Steele).
    s_ll[tid] = ll_sum;
    s_ct[tid] = valid ? 1.0f : 0.0f;
    s_id[tid] = img;
    __syncthreads();
    #pragma unroll
    for (int d = 1; d < 256; d <<= 1) {
        float a = 0.0f, c = 0.0f;
        if (tid >= d && s_id[tid] == s_id[tid - d]) {
            a = s_ll[tid - d];
            c = s_ct[tid - d];
        }
        __syncthreads();
        s_ll[tid] += a;
        s_ct[tid] += c;
        __syncthreads();
    }
    if (valid) {
        bool tail = (tid == 255) || (s_id[tid + 1] != img);
        if (tail) {
            atomicAdd(&img_sum[img], s_ll[tid]);
            atomicAdd(&img_cnt[img], s_ct[tid]);
        }
    }
}

// ---------------- Kernel C: finalize scalars ----------------
__global__ __launch_bounds__(256) void k_final(
    const float* __restrict__ img_sum,
    const float* __restrict__ img_cnt,
    const float* __restrict__ kl_sum,
    float* __restrict__ out)
{
    __shared__ float sred[256];
    float acc = 0.0f;
    for (int i = threadIdx.x; i < N_IMAGES; i += 256) {
        acc += img_sum[i] / fmaxf(img_cnt[i], 1.0f);
    }
    sred[threadIdx.x] = acc;
    __syncthreads();
    #pragma unroll
    for (int s = 128; s > 0; s >>= 1) {
        if (threadIdx.x < s) sred[threadIdx.x] += sred[threadIdx.x + s];
        __syncthreads();
    }
    if (threadIdx.x == 0) {
        float mean_ll = sred[0] / ((float)MC * (float)N_IMAGES);
        out[N_REFLNS]     = -mean_ll;
        out[N_REFLNS + 1] = kl_sum[0] * (1.0f / (float)N_RAC);
    }
}

extern "C" void kernel_launch(void* const* d_in, const int* in_sizes, int n_in,
                              void* d_out, int out_size, void* d_ws, size_t ws_size,
                              hipStream_t stream) {
    const float* q_loc       = (const float*)d_in[0];
    const float* q_log_scale = (const float*)d_in[1];
    const float* eps         = (const float*)d_in[2];
    const float* metadata    = (const float*)d_in[3];
    const float* W1          = (const float*)d_in[4];
    const float* b1          = (const float*)d_in[5];
    const float* W2          = (const float*)d_in[6];
    const float* b2          = (const float*)d_in[7];
    const float* iobs        = (const float*)d_in[8];
    const float* sigiobs     = (const float*)d_in[9];
    const int*   image_id    = (const int*)d_in[10];
    const int*   miller_id   = (const int*)d_in[11];
    float* out = (float*)d_out;

    char* ws = (char*)d_ws;
    float* img_sum = (float*)ws;                 // 8192
    float* img_cnt = img_sum + N_IMAGES;         // 8192
    float* kl_sum  = img_cnt + N_IMAGES;         // 1
    const size_t z_off = 65664;
    bool has_z = (ws_size >= z_off + (size_t)N_RAC * MC * sizeof(float));
    float* zT = has_z ? (float*)(ws + z_off) : nullptr;

    hipMemsetAsync(d_ws, 0, (2 * N_IMAGES + 1) * sizeof(float), stream);

    k_z_kl<<<(N_RAC / 4 + 255) / 256, 256, 0, stream>>>(q_loc, q_log_scale, eps, zT, kl_sum);

    if (has_z) {
        k_main<true><<<(N_REFLNS + 255) / 256, 256, 0, stream>>>(
            metadata, W1, b1, W2, b2, iobs, sigiobs, image_id, miller_id,
            zT, q_loc, q_log_scale, eps, out, img_sum, img_cnt);
    } else {
        k_main<false><<<(N_REFLNS + 255) / 256, 256, 0, stream>>>(
            metadata, W1, b1, W2, b2, iobs, sigiobs, image_id, miller_id,
            nullptr, q_loc, q_log_scale, eps, out, img_sum, img_cnt);
    }

    k_final<<<1, 256, 0, stream>>>(img_sum, img_cnt, kl_sum, out);
}

// Round 4
// 338.158 us; speedup vs baseline: 1.8417x; 1.8417x over previous
//
#include <hip/hip_runtime.h>
#include <math.h>

#define N_REFLNS 2000000
#define N_IMAGES 8192
#define N_RAC    1000000
#define MC       8
#define D_META   16
#define HIDDEN   32
#define LOG_2PI  1.8378770664093453f

// Workspace layout (bytes):
//   [0, 32768)          img_sum   (8192 f32)
//   [32768, 65536)      img_cnt   (8192 f32)
//   [65536, 65540)      kl_sum    (1 f32)
//   [65664, 65664+32e6) zT        (N_RAC x MC f32, transposed z for 32B gathers)

typedef __attribute__((ext_vector_type(8))) short bf16x8;
typedef __attribute__((ext_vector_type(4))) float f32x4;

__device__ __forceinline__ float softplus_f(float x) {
    return fmaxf(x, 0.0f) + log1pf(expf(-fabsf(x)));
}

__device__ __forceinline__ unsigned short bf16_rne(float x) {
    unsigned u = __float_as_uint(x);
    unsigned r = u + 0x7FFFu + ((u >> 16) & 1u);
    return (unsigned short)(r >> 16);
}
__device__ __forceinline__ float bf16_f32(unsigned short b) {
    return __uint_as_float(((unsigned)b) << 16);
}
// f32 -> (hi, lo) bf16 pair; hi+lo reproduces x to ~2^-17 rel.
__device__ __forceinline__ void split8(const float* x, bf16x8& hi, bf16x8& lo) {
    #pragma unroll
    for (int j = 0; j < 8; j++) {
        unsigned short h = bf16_rne(x[j]);
        float hf = bf16_f32(h);
        unsigned short l = bf16_rne(x[j] - hf);
        hi[j] = (short)h;
        lo[j] = (short)l;
    }
}

#define MFMA(A, B, C) __builtin_amdgcn_mfma_f32_16x16x32_bf16(A, B, C, 0, 0, 0)

// ---------------- Kernel A: zT + KL, 4 RAC entries per thread ----------------
__global__ __launch_bounds__(256) void k_z_kl(
    const float* __restrict__ q_loc,
    const float* __restrict__ q_log_scale,
    const float* __restrict__ eps,
    float* __restrict__ zT,          // may be null (fallback)
    float* __restrict__ kl_sum)
{
    int t = blockIdx.x * 256 + threadIdx.x;
    int r0 = t * 4;
    float kl = 0.0f;
    if (r0 < N_RAC) {
        float4 ql  = *(const float4*)(q_loc + r0);
        float4 qls = *(const float4*)(q_log_scale + r0);
        float4 qs;
        qs.x = expf(qls.x); qs.y = expf(qls.y);
        qs.z = expf(qls.z); qs.w = expf(qls.w);
        kl = 0.5f * (qs.x * qs.x + ql.x * ql.x - 1.0f) - qls.x
           + 0.5f * (qs.y * qs.y + ql.y * ql.y - 1.0f) - qls.y
           + 0.5f * (qs.z * qs.z + ql.z * ql.z - 1.0f) - qls.z
           + 0.5f * (qs.w * qs.w + ql.w * ql.w - 1.0f) - qls.w;
        if (zT) {
            float zr[4][MC];
            #pragma unroll
            for (int s = 0; s < MC; s++) {
                float4 e = *(const float4*)(eps + (size_t)s * N_RAC + r0);
                zr[0][s] = ql.x + qs.x * e.x;
                zr[1][s] = ql.y + qs.y * e.y;
                zr[2][s] = ql.z + qs.z * e.z;
                zr[3][s] = ql.w + qs.w * e.w;
            }
            #pragma unroll
            for (int r = 0; r < 4; r++) {
                float4* dst = (float4*)(zT + (size_t)(r0 + r) * MC);
                dst[0] = make_float4(zr[r][0], zr[r][1], zr[r][2], zr[r][3]);
                dst[1] = make_float4(zr[r][4], zr[r][5], zr[r][6], zr[r][7]);
            }
        }
    }
    __shared__ float sred[256];
    sred[threadIdx.x] = kl;
    __syncthreads();
    #pragma unroll
    for (int s = 128; s > 0; s >>= 1) {
        if (threadIdx.x < s) sred[threadIdx.x] += sred[threadIdx.x + s];
        __syncthreads();
    }
    if (threadIdx.x == 0) atomicAdd(kl_sum, sred[0]);
}

// ---------------- Kernel B: MFMA MLP + likelihood -----------------------------
// Block = 4 waves; each wave owns 64 reflections (4 M-tiles of 16).
// Layer1: D(16x32) = meta(16x16, K-padded to 32) @ W1, bf16 hi/lo split (3 MFMAs
// per product) for ~f32 accuracy. H -> LDS (f32) -> A-frag for layer2.
// Layer2: logits(16x8) = H(16x32) @ W2 via 16x16x32, N padded to 16.
// Logits -> LDS -> one reflection per lane for the likelihood epilogue.
template <bool HAS_Z>
__global__ __launch_bounds__(256) void k_main(
    const float* __restrict__ metadata,
    const float* __restrict__ W1, const float* __restrict__ b1,
    const float* __restrict__ W2, const float* __restrict__ b2,
    const float* __restrict__ iobs, const float* __restrict__ sigiobs,
    const int* __restrict__ image_id, const int* __restrict__ miller_id,
    const float* __restrict__ zT,
    const float* __restrict__ q_loc, const float* __restrict__ q_log_scale,
    const float* __restrict__ eps,
    float* __restrict__ out_ipred,
    float* __restrict__ img_sum, float* __restrict__ img_cnt)
{
    // H tile: 16 rows x 32 cols, stride 36 (bank-conflict-free, 16B-aligned rows)
    __shared__ __align__(16) float sH[4][16 * 36];
    // logits: per wave 4 tiles x 16 rows x stride 10
    __shared__ __align__(16) float sL[4][4 * 160];
    __shared__ int   s_id[256];
    __shared__ float s_ll[256];
    __shared__ float s_ct[256];

    int tid  = threadIdx.x;
    int wave = tid >> 6;
    int lane = tid & 63;
    int q    = lane >> 4;    // quad 0..3
    int col  = lane & 15;

    // ---- weight fragments (loaded once; tiny, L1/L2 cached) ----
    bf16x8 W1h[2], W1l[2];   // B-frag per hidden-half: B[k][n], k=q*8+j, n=col
    {
        float tmp[8];
        #pragma unroll
        for (int h2 = 0; h2 < 2; h2++) {
            #pragma unroll
            for (int j = 0; j < 8; j++) {
                int k = q * 8 + j;
                tmp[j] = (k < D_META) ? W1[k * HIDDEN + h2 * 16 + col] : 0.0f;
            }
            split8(tmp, W1h[h2], W1l[h2]);
        }
    }
    bf16x8 W2h, W2l;         // B[k][n] = W2[k*8+n], n=col<8 else 0
    {
        float tmp[8];
        #pragma unroll
        for (int j = 0; j < 8; j++) {
            int k = q * 8 + j;
            tmp[j] = (col < MC) ? W2[k * MC + col] : 0.0f;
        }
        split8(tmp, W2h, W2l);
    }
    float b1v0 = b1[col];
    float b1v1 = b1[16 + col];
    float b2v  = (col < MC) ? b2[col] : 0.0f;

    int base_w = blockIdx.x * 256 + wave * 64;
    float* Hbuf = &sH[wave][0];
    float* Lbuf = &sL[wave][0];

    #pragma unroll
    for (int t = 0; t < 4; t++) {
        int rowbase = base_w + t * 16;
        // ---- A-frag: metadata row m=col, k=q*8+j (quads 2,3 are K-padding) ----
        bf16x8 Ah, Al;
        {
            float tmp[8];
            if (q < 2) {
                int r = rowbase + col;
                if (r >= N_REFLNS) r = N_REFLNS - 1;   // tail clamp (masked later)
                const float4* p = (const float4*)(metadata + (size_t)r * D_META + q * 8);
                float4 v0 = p[0], v1 = p[1];
                tmp[0] = v0.x; tmp[1] = v0.y; tmp[2] = v0.z; tmp[3] = v0.w;
                tmp[4] = v1.x; tmp[5] = v1.y; tmp[6] = v1.z; tmp[7] = v1.w;
            } else {
                #pragma unroll
                for (int j = 0; j < 8; j++) tmp[j] = 0.0f;
            }
            split8(tmp, Ah, Al);
        }

        // ---- layer 1: two hidden halves, hi/lo 3-term MFMA ----
        #pragma unroll
        for (int h2 = 0; h2 < 2; h2++) {
            float b1x = h2 ? b1v1 : b1v0;
            f32x4 c = {b1x, b1x, b1x, b1x};
            c = MFMA(Al, (h2 ? W1h[1] : W1h[0]), c);
            c = MFMA(Ah, (h2 ? W1l[1] : W1l[0]), c);
            c = MFMA(Ah, (h2 ? W1h[1] : W1h[0]), c);
            // relu + store H[m][k]: m=q*4+r, k=h2*16+col
            #pragma unroll
            for (int r = 0; r < 4; r++) {
                Hbuf[(q * 4 + r) * 36 + h2 * 16 + col] = fmaxf(c[r], 0.0f);
            }
        }

        // ---- H -> A-frag (same wave; lgkmcnt ordering, no barrier needed) ----
        bf16x8 Hh, Hl;
        {
            const float4* hp = (const float4*)(Hbuf + col * 36 + q * 8);
            float4 a0 = hp[0], a1 = hp[1];
            float tmp[8] = {a0.x, a0.y, a0.z, a0.w, a1.x, a1.y, a1.z, a1.w};
            split8(tmp, Hh, Hl);
        }

        // ---- layer 2 ----
        f32x4 c2 = {b2v, b2v, b2v, b2v};
        c2 = MFMA(Hl, W2h, c2);
        c2 = MFMA(Hh, W2l, c2);
        c2 = MFMA(Hh, W2h, c2);
        if (col < MC) {
            #pragma unroll
            for (int r = 0; r < 4; r++) {
                Lbuf[t * 160 + (q * 4 + r) * 10 + col] = c2[r];
            }
        }
    }

    // ---- epilogue: one reflection per lane ----
    int n = base_w + lane;
    bool valid = (n < N_REFLNS);
    float ll_sum = 0.0f;
    int img = -1;

    if (valid) {
        float lg[MC];
        {
            const float2* lp = (const float2*)(Lbuf + (lane >> 4) * 160 + (lane & 15) * 10);
            float2 p0 = lp[0], p1 = lp[1], p2 = lp[2], p3 = lp[3];
            lg[0] = p0.x; lg[1] = p0.y; lg[2] = p1.x; lg[3] = p1.y;
            lg[4] = p2.x; lg[5] = p2.y; lg[6] = p3.x; lg[7] = p3.y;
        }
        int m = miller_id[n];
        float io = iobs[n];
        float sg = sigiobs[n];
        img = image_id[n];

        float f[MC];
        if (HAS_Z) {
            const float4* zp = (const float4*)(zT + (size_t)m * MC);
            float4 z0 = zp[0], z1 = zp[1];
            f[0] = z0.x; f[1] = z0.y; f[2] = z0.z; f[3] = z0.w;
            f[4] = z1.x; f[5] = z1.y; f[6] = z1.z; f[7] = z1.w;
        } else {
            float qlv = q_loc[m];
            float qsv = expf(q_log_scale[m]);
            #pragma unroll
            for (int s = 0; s < MC; s++) f[s] = qlv + qsv * eps[(size_t)s * N_RAC + m];
        }

        float inv_sg = 1.0f / sg;
        float sum_ip = 0.0f, sum_r2 = 0.0f;
        #pragma unroll
        for (int s = 0; s < MC; s++) {
            float sc = softplus_f(lg[s]);
            float ip = f[s] * f[s] * sc;
            sum_ip += ip;
            float r = (ip - io) * inv_sg;
            sum_r2 = fmaf(r, r, sum_r2);
        }
        out_ipred[n] = sum_ip * (1.0f / MC);
        ll_sum = -0.5f * sum_r2 - (float)MC * (logf(sg) + 0.5f * LOG_2PI);
    }

    // ---- segmented inclusive scan over sorted image ids ----
    s_ll[tid] = ll_sum;
    s_ct[tid] = valid ? 1.0f : 0.0f;
    s_id[tid] = img;
    __syncthreads();
    #pragma unroll
    for (int d = 1; d < 256; d <<= 1) {
        float a = 0.0f, c = 0.0f;
        if (tid >= d && s_id[tid] == s_id[tid - d]) {
            a = s_ll[tid - d];
            c = s_ct[tid - d];
        }
        __syncthreads();
        s_ll[tid] += a;
        s_ct[tid] += c;
        __syncthreads();
    }
    if (valid) {
        bool tail = (tid == 255) || (s_id[tid + 1] != img);
        if (tail) {
            atomicAdd(&img_sum[img], s_ll[tid]);
            atomicAdd(&img_cnt[img], s_ct[tid]);
        }
    }
}

// ---------------- Kernel C: finalize scalars ----------------
__global__ __launch_bounds__(256) void k_final(
    const float* __restrict__ img_sum,
    const float* __restrict__ img_cnt,
    const float* __restrict__ kl_sum,
    float* __restrict__ out)
{
    __shared__ float sred[256];
    float acc = 0.0f;
    for (int i = threadIdx.x; i < N_IMAGES; i += 256) {
        acc += img_sum[i] / fmaxf(img_cnt[i], 1.0f);
    }
    sred[threadIdx.x] = acc;
    __syncthreads();
    #pragma unroll
    for (int s = 128; s > 0; s >>= 1) {
        if (threadIdx.x < s) sred[threadIdx.x] += sred[threadIdx.x + s];
        __syncthreads();
    }
    if (threadIdx.x == 0) {
        float mean_ll = sred[0] / ((float)MC * (float)N_IMAGES);
        out[N_REFLNS]     = -mean_ll;
        out[N_REFLNS + 1] = kl_sum[0] * (1.0f / (float)N_RAC);
    }
}

extern "C" void kernel_launch(void* const* d_in, const int* in_sizes, int n_in,
                              void* d_out, int out_size, void* d_ws, size_t ws_size,
                              hipStream_t stream) {
    const float* q_loc       = (const float*)d_in[0];
    const float* q_log_scale = (const float*)d_in[1];
    const float* eps         = (const float*)d_in[2];
    const float* metadata    = (const float*)d_in[3];
    const float* W1          = (const float*)d_in[4];
    const float* b1          = (const float*)d_in[5];
    const float* W2          = (const float*)d_in[6];
    const float* b2          = (const float*)d_in[7];
    const float* iobs        = (const float*)d_in[8];
    const float* sigiobs     = (const float*)d_in[9];
    const int*   image_id    = (const int*)d_in[10];
    const int*   miller_id   = (const int*)d_in[11];
    float* out = (float*)d_out;

    char* ws = (char*)d_ws;
    float* img_sum = (float*)ws;                 // 8192
    float* img_cnt = img_sum + N_IMAGES;         // 8192
    float* kl_sum  = img_cnt + N_IMAGES;         // 1
    const size_t z_off = 65664;
    bool has_z = (ws_size >= z_off + (size_t)N_RAC * MC * sizeof(float));
    float* zT = has_z ? (float*)(ws + z_off) : nullptr;

    hipMemsetAsync(d_ws, 0, (2 * N_IMAGES + 1) * sizeof(float), stream);

    k_z_kl<<<(N_RAC / 4 + 255) / 256, 256, 0, stream>>>(q_loc, q_log_scale, eps, zT, kl_sum);

    if (has_z) {
        k_main<true><<<(N_REFLNS + 255) / 256, 256, 0, stream>>>(
            metadata, W1, b1, W2, b2, iobs, sigiobs, image_id, miller_id,
            zT, q_loc, q_log_scale, eps, out, img_sum, img_cnt);
    } else {
        k_main<false><<<(N_REFLNS + 255) / 256, 256, 0, stream>>>(
            metadata, W1, b1, W2, b2, iobs, sigiobs, image_id, miller_id,
            nullptr, q_loc, q_log_scale, eps, out, img_sum, img_cnt);
    }

    k_final<<<1, 256, 0, stream>>>(img_sum, img_cnt, kl_sum, out);
}

// Round 5
// 292.325 us; speedup vs baseline: 2.1305x; 1.1568x over previous
//
#include <hip/hip_runtime.h>
#include <hip/hip_bf16.h>
#include <math.h>

#define N_REFLNS 2000000
#define N_IMAGES 8192
#define N_RAC    1000000
#define MC       8
#define D_META   16
#define HIDDEN   32
#define LOG_2PI  1.8378770664093453f
#define LOG2E    1.44269504089f
#define LN2      0.69314718056f

// Workspace layout (bytes):
//   [0, 32768)          img_sum   (8192 f32)
//   [32768, 65536)      img_cnt   (8192 f32)
//   [65536, 65540)      kl_sum    (1 f32)
//   [65664, 65664+32e6) zT        (N_RAC x MC f32, transposed z for 32B gathers)

typedef __attribute__((ext_vector_type(8)))  short bf16x8;
typedef __attribute__((ext_vector_type(4)))  float f32x4;
typedef __attribute__((ext_vector_type(16))) float f32x16;

#define MFMA16(A, B, C) __builtin_amdgcn_mfma_f32_16x16x32_bf16(A, B, C, 0, 0, 0)
#define MFMA32(A, B, C) __builtin_amdgcn_mfma_f32_32x32x16_bf16(A, B, C, 0, 0, 0)

union B8 { bf16x8 v; unsigned u[4]; };

// Dekker-style split: hi = trunc-to-bf16 (residual captured EXACTLY by lo; no
// need for RNE on hi), lo = trunc(x - hi). Total rel err ~2^-17. Pure bit-ops.
__device__ __forceinline__ void split_hilo(const float* x, bf16x8& hi, bf16x8& lo) {
    B8 h, l;
    #pragma unroll
    for (int p = 0; p < 4; p++) {
        unsigned u0 = __float_as_uint(x[2 * p]);
        unsigned u1 = __float_as_uint(x[2 * p + 1]);
        unsigned hf0 = u0 & 0xFFFF0000u;
        unsigned hf1 = u1 & 0xFFFF0000u;
        h.u[p] = (u0 >> 16) | hf1;
        float d0 = x[2 * p]     - __uint_as_float(hf0);
        float d1 = x[2 * p + 1] - __uint_as_float(hf1);
        l.u[p] = (__float_as_uint(d0) >> 16) | (__float_as_uint(d1) & 0xFFFF0000u);
    }
    hi = h.v; lo = l.v;
}

// RNE pack via packed hw conversion (v_cvt_pk_bf16_f32 on gfx950).
__device__ __forceinline__ bf16x8 pack8_rne(float4 a0, float4 a1) {
    B8 r;
    __hip_bfloat162 t0 = __float22bfloat162_rn(make_float2(a0.x, a0.y));
    __hip_bfloat162 t1 = __float22bfloat162_rn(make_float2(a0.z, a0.w));
    __hip_bfloat162 t2 = __float22bfloat162_rn(make_float2(a1.x, a1.y));
    __hip_bfloat162 t3 = __float22bfloat162_rn(make_float2(a1.z, a1.w));
    r.u[0] = reinterpret_cast<unsigned&>(t0);
    r.u[1] = reinterpret_cast<unsigned&>(t1);
    r.u[2] = reinterpret_cast<unsigned&>(t2);
    r.u[3] = reinterpret_cast<unsigned&>(t3);
    return r.v;
}

// softplus via native v_exp/v_log (log2-domain): ~8 VALU, abs err ~1e-7*scale
__device__ __forceinline__ float softplus_fast(float x) {
    float t = __builtin_amdgcn_exp2f(-fabsf(x) * LOG2E);
    return fmaxf(x, 0.0f) + LN2 * __builtin_amdgcn_logf(1.0f + t);
}

// ---------------- Kernel A: zT + KL, 4 RAC entries per thread ----------------
__global__ __launch_bounds__(256) void k_z_kl(
    const float* __restrict__ q_loc,
    const float* __restrict__ q_log_scale,
    const float* __restrict__ eps,
    float* __restrict__ zT,          // may be null (fallback)
    float* __restrict__ kl_sum)
{
    int t = blockIdx.x * 256 + threadIdx.x;
    int r0 = t * 4;
    float kl = 0.0f;
    if (r0 < N_RAC) {
        float4 ql  = *(const float4*)(q_loc + r0);
        float4 qls = *(const float4*)(q_log_scale + r0);
        float4 qs;
        qs.x = expf(qls.x); qs.y = expf(qls.y);
        qs.z = expf(qls.z); qs.w = expf(qls.w);
        kl = 0.5f * (qs.x * qs.x + ql.x * ql.x - 1.0f) - qls.x
           + 0.5f * (qs.y * qs.y + ql.y * ql.y - 1.0f) - qls.y
           + 0.5f * (qs.z * qs.z + ql.z * ql.z - 1.0f) - qls.z
           + 0.5f * (qs.w * qs.w + ql.w * ql.w - 1.0f) - qls.w;
        if (zT) {
            float zr[4][MC];
            #pragma unroll
            for (int s = 0; s < MC; s++) {
                float4 e = *(const float4*)(eps + (size_t)s * N_RAC + r0);
                zr[0][s] = ql.x + qs.x * e.x;
                zr[1][s] = ql.y + qs.y * e.y;
                zr[2][s] = ql.z + qs.z * e.z;
                zr[3][s] = ql.w + qs.w * e.w;
            }
            #pragma unroll
            for (int r = 0; r < 4; r++) {
                float4* dst = (float4*)(zT + (size_t)(r0 + r) * MC);
                dst[0] = make_float4(zr[r][0], zr[r][1], zr[r][2], zr[r][3]);
                dst[1] = make_float4(zr[r][4], zr[r][5], zr[r][6], zr[r][7]);
            }
        }
    }
    __shared__ float sred[256];
    sred[threadIdx.x] = kl;
    __syncthreads();
    #pragma unroll
    for (int s = 128; s > 0; s >>= 1) {
        if (threadIdx.x < s) sred[threadIdx.x] += sred[threadIdx.x + s];
        __syncthreads();
    }
    if (threadIdx.x == 0) atomicAdd(kl_sum, sred[0]);
}

// ---------------- Kernel B: MFMA MLP + likelihood -----------------------------
// Block = 4 waves; each wave owns 64 reflections = 2 supertiles of 32 rows.
// Layer1 per supertile: D(32x32) = meta(32xK16) @ W1 via mfma_32x32x16_bf16,
//   hi/lo 3-term. K=16 exact (no padding). H -> LDS row-major (stride 36).
// Layer2 per 16-row tile: logits = Hh(16xK32) @ W2(hi+lo) via mfma_16x16x32.
// Logits -> LDS -> one reflection per lane for the epilogue (R4-verified path).
template <bool HAS_Z>
__global__ __launch_bounds__(256) void k_main(
    const float* __restrict__ metadata,
    const float* __restrict__ W1, const float* __restrict__ b1,
    const float* __restrict__ W2, const float* __restrict__ b2,
    const float* __restrict__ iobs, const float* __restrict__ sigiobs,
    const int* __restrict__ image_id, const int* __restrict__ miller_id,
    const float* __restrict__ zT,
    const float* __restrict__ q_loc, const float* __restrict__ q_log_scale,
    const float* __restrict__ eps,
    float* __restrict__ out_ipred,
    float* __restrict__ img_sum, float* __restrict__ img_cnt)
{
    __shared__ __align__(16) float sH[4][32 * 36];   // per-wave H supertile
    __shared__ __align__(16) float sL[4][4 * 160];   // per-wave logits, 4 tiles
    __shared__ int   s_id[256];
    __shared__ float s_ll[256];
    __shared__ float s_ct[256];

    int tid  = threadIdx.x;
    int wave = tid >> 6;
    int lane = tid & 63;
    int n31  = lane & 31;   // 32x32: A-row (m) / B-col (n) / D-col
    int kh   = lane >> 5;   // 32x32: k-half (k = kh*8 + j)
    int q    = lane >> 4;   // 16x16: quad 0..3
    int c16  = lane & 15;   // 16x16: A-row / D-col

    // ---- layer-1 weights as 32x32x16 B-frags: B[k][n], k=kh*8+j, n=n31 ----
    bf16x8 W1h, W1l;
    {
        float tmp[8];
        #pragma unroll
        for (int j = 0; j < 8; j++) tmp[j] = W1[(kh * 8 + j) * HIDDEN + n31];
        split_hilo(tmp, W1h, W1l);
    }
    float b1v = b1[n31];

    // ---- layer-2 weights as 16x16x32 B-frags: B[k][n], k=q*8+j, n=c16 ----
    bf16x8 W2h, W2l;
    {
        float tmp[8];
        #pragma unroll
        for (int j = 0; j < 8; j++) tmp[j] = (c16 < MC) ? W2[(q * 8 + j) * MC + c16] : 0.0f;
        split_hilo(tmp, W2h, W2l);
    }
    float b2v = (c16 < MC) ? b2[c16] : 0.0f;

    int base_w = blockIdx.x * 256 + wave * 64;
    float* Hb = &sH[wave][0];
    float* Lb = &sL[wave][0];

    #pragma unroll
    for (int st = 0; st < 2; st++) {
        int rowbase = base_w + st * 32;
        // ---- A-frag: meta[m][k], m=n31, k=kh*8+j (K=16 exact) ----
        int r = rowbase + n31;
        if (r > N_REFLNS - 1) r = N_REFLNS - 1;   // tail clamp (masked later)
        const float4* mp = (const float4*)(metadata + (size_t)r * D_META + kh * 8);
        float4 a0 = mp[0], a1 = mp[1];
        float av[8] = {a0.x, a0.y, a0.z, a0.w, a1.x, a1.y, a1.z, a1.w};
        bf16x8 Ah, Al;
        split_hilo(av, Ah, Al);

        // ---- layer 1: one 32x32 tile, 3-term hi/lo ----
        f32x16 cc;
        #pragma unroll
        for (int i = 0; i < 16; i++) cc[i] = b1v;
        cc = MFMA32(Al, W1h, cc);
        cc = MFMA32(Ah, W1l, cc);
        cc = MFMA32(Ah, W1h, cc);
        // relu + store: row=(i&3)+8*(i>>2)+4*kh, col=n31
        #pragma unroll
        for (int i = 0; i < 16; i++) {
            int row = (i & 3) + 8 * (i >> 2) + 4 * kh;
            Hb[row * 36 + n31] = fmaxf(cc[i], 0.0f);
        }

        // ---- layer 2: two 16-row tiles (same-wave LDS ordering) ----
        #pragma unroll
        for (int t2 = 0; t2 < 2; t2++) {
            const float4* hp = (const float4*)(Hb + (t2 * 16 + c16) * 36 + q * 8);
            bf16x8 Hh = pack8_rne(hp[0], hp[1]);
            f32x4 c2 = {b2v, b2v, b2v, b2v};
            c2 = MFMA16(Hh, W2l, c2);
            c2 = MFMA16(Hh, W2h, c2);
            if (c16 < MC) {
                #pragma unroll
                for (int rr = 0; rr < 4; rr++) {
                    Lb[(st * 2 + t2) * 160 + (q * 4 + rr) * 10 + c16] = c2[rr];
                }
            }
        }
    }

    // ---- epilogue: one reflection per lane ----
    int n = base_w + lane;
    bool valid = (n < N_REFLNS);
    float ll_sum = 0.0f;
    int img = -1;

    if (valid) {
        float lg[MC];
        {
            const float2* lp = (const float2*)(Lb + (lane >> 4) * 160 + c16 * 10);
            float2 p0 = lp[0], p1 = lp[1], p2 = lp[2], p3 = lp[3];
            lg[0] = p0.x; lg[1] = p0.y; lg[2] = p1.x; lg[3] = p1.y;
            lg[4] = p2.x; lg[5] = p2.y; lg[6] = p3.x; lg[7] = p3.y;
        }
        int m = miller_id[n];
        float io = iobs[n];
        float sg = sigiobs[n];
        img = image_id[n];

        float f[MC];
        if (HAS_Z) {
            const float4* zp = (const float4*)(zT + (size_t)m * MC);
            float4 z0 = zp[0], z1 = zp[1];
            f[0] = z0.x; f[1] = z0.y; f[2] = z0.z; f[3] = z0.w;
            f[4] = z1.x; f[5] = z1.y; f[6] = z1.z; f[7] = z1.w;
        } else {
            float qlv = q_loc[m];
            float qsv = expf(q_log_scale[m]);
            #pragma unroll
            for (int s = 0; s < MC; s++) f[s] = qlv + qsv * eps[(size_t)s * N_RAC + m];
        }

        float sum_ip = 0.0f, sum_d2 = 0.0f;
        #pragma unroll
        for (int s = 0; s < MC; s++) {
            float sc = softplus_fast(lg[s]);
            float ip = f[s] * f[s] * sc;
            sum_ip += ip;
            float d = ip - io;
            sum_d2 = fmaf(d, d, sum_d2);
        }
        float inv = __builtin_amdgcn_rcpf(sg);
        out_ipred[n] = sum_ip * (1.0f / MC);
        ll_sum = -0.5f * sum_d2 * inv * inv
                 - (float)MC * (0.5f * LOG_2PI)
                 - (float)MC * (LN2 * __builtin_amdgcn_logf(sg));
    }

    // ---- segmented inclusive scan over sorted image ids ----
    s_ll[tid] = ll_sum;
    s_ct[tid] = valid ? 1.0f : 0.0f;
    s_id[tid] = img;
    __syncthreads();
    #pragma unroll
    for (int d = 1; d < 256; d <<= 1) {
        float a = 0.0f, c = 0.0f;
        if (tid >= d && s_id[tid] == s_id[tid - d]) {
            a = s_ll[tid - d];
            c = s_ct[tid - d];
        }
        __syncthreads();
        s_ll[tid] += a;
        s_ct[tid] += c;
        __syncthreads();
    }
    if (valid) {
        bool tail = (tid == 255) || (s_id[tid + 1] != img);
        if (tail) {
            atomicAdd(&img_sum[img], s_ll[tid]);
            atomicAdd(&img_cnt[img], s_ct[tid]);
        }
    }
}

// ---------------- Kernel C: finalize scalars ----------------
__global__ __launch_bounds__(256) void k_final(
    const float* __restrict__ img_sum,
    const float* __restrict__ img_cnt,
    const float* __restrict__ kl_sum,
    float* __restrict__ out)
{
    __shared__ float sred[256];
    float acc = 0.0f;
    for (int i = threadIdx.x; i < N_IMAGES; i += 256) {
        acc += img_sum[i] / fmaxf(img_cnt[i], 1.0f);
    }
    sred[threadIdx.x] = acc;
    __syncthreads();
    #pragma unroll
    for (int s = 128; s > 0; s >>= 1) {
        if (threadIdx.x < s) sred[threadIdx.x] += sred[threadIdx.x + s];
        __syncthreads();
    }
    if (threadIdx.x == 0) {
        float mean_ll = sred[0] / ((float)MC * (float)N_IMAGES);
        out[N_REFLNS]     = -mean_ll;
        out[N_REFLNS + 1] = kl_sum[0] * (1.0f / (float)N_RAC);
    }
}

extern "C" void kernel_launch(void* const* d_in, const int* in_sizes, int n_in,
                              void* d_out, int out_size, void* d_ws, size_t ws_size,
                              hipStream_t stream) {
    const float* q_loc       = (const float*)d_in[0];
    const float* q_log_scale = (const float*)d_in[1];
    const float* eps         = (const float*)d_in[2];
    const float* metadata    = (const float*)d_in[3];
    const float* W1          = (const float*)d_in[4];
    const float* b1          = (const float*)d_in[5];
    const float* W2          = (const float*)d_in[6];
    const float* b2          = (const float*)d_in[7];
    const float* iobs        = (const float*)d_in[8];
    const float* sigiobs     = (const float*)d_in[9];
    const int*   image_id    = (const int*)d_in[10];
    const int*   miller_id   = (const int*)d_in[11];
    float* out = (float*)d_out;

    char* ws = (char*)d_ws;
    float* img_sum = (float*)ws;                 // 8192
    float* img_cnt = img_sum + N_IMAGES;         // 8192
    float* kl_sum  = img_cnt + N_IMAGES;         // 1
    const size_t z_off = 65664;
    bool has_z = (ws_size >= z_off + (size_t)N_RAC * MC * sizeof(float));
    float* zT = has_z ? (float*)(ws + z_off) : nullptr;

    hipMemsetAsync(d_ws, 0, (2 * N_IMAGES + 1) * sizeof(float), stream);

    k_z_kl<<<(N_RAC / 4 + 255) / 256, 256, 0, stream>>>(q_loc, q_log_scale, eps, zT, kl_sum);

    if (has_z) {
        k_main<true><<<(N_REFLNS + 255) / 256, 256, 0, stream>>>(
            metadata, W1, b1, W2, b2, iobs, sigiobs, image_id, miller_id,
            zT, q_loc, q_log_scale, eps, out, img_sum, img_cnt);
    } else {
        k_main<false><<<(N_REFLNS + 255) / 256, 256, 0, stream>>>(
            metadata, W1, b1, W2, b2, iobs, sigiobs, image_id, miller_id,
            nullptr, q_loc, q_log_scale, eps, out, img_sum, img_cnt);
    }

    k_final<<<1, 256, 0, stream>>>(img_sum, img_cnt, kl_sum, out);
}

// Round 6
// 287.928 us; speedup vs baseline: 2.1630x; 1.0153x over previous
//
#include <hip/hip_runtime.h>
#include <hip/hip_bf16.h>
#include <math.h>

#define N_REFLNS 2000000
#define N_IMAGES 8192
#define N_RAC    1000000
#define MC       8
#define D_META   16
#define HIDDEN   32
#define LOG_2PI  1.8378770664093453f
#define LOG2E    1.44269504089f
#define LN2      0.69314718056f

// Workspace layout (bytes):
//   [0, 32768)          img_sum   (8192 f32)
//   [32768, 65536)      img_cnt   (8192 f32)
//   [65536, 65540)      kl_sum    (1 f32)
//   [65664, 65664+32e6) zT        (N_RAC x MC f32, transposed z for 32B gathers)

typedef __attribute__((ext_vector_type(8)))  short bf16x8;
typedef __attribute__((ext_vector_type(4)))  float f32x4;
typedef __attribute__((ext_vector_type(16))) float f32x16;

#define MFMA16(A, B, C) __builtin_amdgcn_mfma_f32_16x16x32_bf16(A, B, C, 0, 0, 0)
#define MFMA32(A, B, C) __builtin_amdgcn_mfma_f32_32x32x16_bf16(A, B, C, 0, 0, 0)

union B8 { bf16x8 v; unsigned u[4]; };

// Dekker split: hi = trunc-to-bf16, lo = trunc(x - hi). rel err ~2^-17.
__device__ __forceinline__ void split_hilo(const float* x, bf16x8& hi, bf16x8& lo) {
    B8 h, l;
    #pragma unroll
    for (int p = 0; p < 4; p++) {
        unsigned u0 = __float_as_uint(x[2 * p]);
        unsigned u1 = __float_as_uint(x[2 * p + 1]);
        unsigned hf0 = u0 & 0xFFFF0000u;
        unsigned hf1 = u1 & 0xFFFF0000u;
        h.u[p] = (u0 >> 16) | hf1;
        float d0 = x[2 * p]     - __uint_as_float(hf0);
        float d1 = x[2 * p + 1] - __uint_as_float(hf1);
        l.u[p] = (__float_as_uint(d0) >> 16) | (__float_as_uint(d1) & 0xFFFF0000u);
    }
    hi = h.v; lo = l.v;
}

// RNE pack via packed hw conversion (v_cvt_pk_bf16_f32 on gfx950).
__device__ __forceinline__ bf16x8 pack8_rne(float4 a0, float4 a1) {
    B8 r;
    __hip_bfloat162 t0 = __float22bfloat162_rn(make_float2(a0.x, a0.y));
    __hip_bfloat162 t1 = __float22bfloat162_rn(make_float2(a0.z, a0.w));
    __hip_bfloat162 t2 = __float22bfloat162_rn(make_float2(a1.x, a1.y));
    __hip_bfloat162 t3 = __float22bfloat162_rn(make_float2(a1.z, a1.w));
    r.u[0] = reinterpret_cast<unsigned&>(t0);
    r.u[1] = reinterpret_cast<unsigned&>(t1);
    r.u[2] = reinterpret_cast<unsigned&>(t2);
    r.u[3] = reinterpret_cast<unsigned&>(t3);
    return r.v;
}

// softplus via native v_exp/v_log (log2 domain)
__device__ __forceinline__ float softplus_fast(float x) {
    float t = __builtin_amdgcn_exp2f(-fabsf(x) * LOG2E);
    return fmaxf(x, 0.0f) + LN2 * __builtin_amdgcn_logf(1.0f + t);
}

// ---------------- Kernel A: zT + KL, 4 RAC entries per thread ----------------
__global__ __launch_bounds__(256) void k_z_kl(
    const float* __restrict__ q_loc,
    const float* __restrict__ q_log_scale,
    const float* __restrict__ eps,
    float* __restrict__ zT,          // may be null (fallback)
    float* __restrict__ kl_sum)
{
    int t = blockIdx.x * 256 + threadIdx.x;
    int r0 = t * 4;
    float kl = 0.0f;
    if (r0 < N_RAC) {
        float4 ql  = *(const float4*)(q_loc + r0);
        float4 qls = *(const float4*)(q_log_scale + r0);
        float4 qs;
        qs.x = __builtin_amdgcn_exp2f(qls.x * LOG2E);
        qs.y = __builtin_amdgcn_exp2f(qls.y * LOG2E);
        qs.z = __builtin_amdgcn_exp2f(qls.z * LOG2E);
        qs.w = __builtin_amdgcn_exp2f(qls.w * LOG2E);
        kl = 0.5f * (qs.x * qs.x + ql.x * ql.x - 1.0f) - qls.x
           + 0.5f * (qs.y * qs.y + ql.y * ql.y - 1.0f) - qls.y
           + 0.5f * (qs.z * qs.z + ql.z * ql.z - 1.0f) - qls.z
           + 0.5f * (qs.w * qs.w + ql.w * ql.w - 1.0f) - qls.w;
        if (zT) {
            float zr[4][MC];
            #pragma unroll
            for (int s = 0; s < MC; s++) {
                float4 e = *(const float4*)(eps + (size_t)s * N_RAC + r0);
                zr[0][s] = ql.x + qs.x * e.x;
                zr[1][s] = ql.y + qs.y * e.y;
                zr[2][s] = ql.z + qs.z * e.z;
                zr[3][s] = ql.w + qs.w * e.w;
            }
            #pragma unroll
            for (int r = 0; r < 4; r++) {
                float4* dst = (float4*)(zT + (size_t)(r0 + r) * MC);
                dst[0] = make_float4(zr[r][0], zr[r][1], zr[r][2], zr[r][3]);
                dst[1] = make_float4(zr[r][4], zr[r][5], zr[r][6], zr[r][7]);
            }
        }
    }
    __shared__ float sred[256];
    sred[threadIdx.x] = kl;
    __syncthreads();
    #pragma unroll
    for (int s = 128; s > 0; s >>= 1) {
        if (threadIdx.x < s) sred[threadIdx.x] += sred[threadIdx.x + s];
        __syncthreads();
    }
    if (threadIdx.x == 0) atomicAdd(kl_sum, sred[0]);
}

// ---------------- Kernel B: MFMA MLP + likelihood -----------------------------
// Block = 4 waves; each wave owns 64 reflections = 2 supertiles of 32 rows.
// Per-lane epilogue globals (miller->zT gather, iobs, sig, image_id) are issued
// at wave start so their latency overlaps the MFMA MLP. Per-image reduction is
// a wave-level segmented scan (shfl, no barriers); run tails atomicAdd.
template <bool HAS_Z>
__global__ __launch_bounds__(256) void k_main(
    const float* __restrict__ metadata,
    const float* __restrict__ W1, const float* __restrict__ b1,
    const float* __restrict__ W2, const float* __restrict__ b2,
    const float* __restrict__ iobs, const float* __restrict__ sigiobs,
    const int* __restrict__ image_id, const int* __restrict__ miller_id,
    const float* __restrict__ zT,
    const float* __restrict__ q_loc, const float* __restrict__ q_log_scale,
    const float* __restrict__ eps,
    float* __restrict__ out_ipred,
    float* __restrict__ img_sum, float* __restrict__ img_cnt)
{
    __shared__ __align__(16) float sH[4][32 * 36];   // per-wave H supertile
    __shared__ __align__(16) float sL[4][4 * 160];   // per-wave logits, 4 tiles

    int tid  = threadIdx.x;
    int wave = tid >> 6;
    int lane = tid & 63;
    int n31  = lane & 31;   // 32x32: A-row (m) / B-col (n) / D-col
    int kh   = lane >> 5;   // 32x32: k-half (k = kh*8 + j)
    int q    = lane >> 4;   // 16x16: quad 0..3
    int c16  = lane & 15;   // 16x16: A-row / D-col

    int base_w = blockIdx.x * 256 + wave * 64;

    // ---- EARLY: per-lane epilogue globals + zT gather (overlap with MLP) ----
    int n = base_w + lane;
    bool valid = (n < N_REFLNS);
    int nc = valid ? n : (N_REFLNS - 1);
    int m    = miller_id[nc];
    float io = iobs[nc];
    float sg = sigiobs[nc];
    int img  = image_id[nc];
    float f[MC];
    if (HAS_Z) {
        const float4* zp = (const float4*)(zT + (size_t)m * MC);
        float4 z0 = zp[0], z1 = zp[1];
        f[0] = z0.x; f[1] = z0.y; f[2] = z0.z; f[3] = z0.w;
        f[4] = z1.x; f[5] = z1.y; f[6] = z1.z; f[7] = z1.w;
    } else {
        float qlv = q_loc[m];
        float qsv = expf(q_log_scale[m]);
        #pragma unroll
        for (int s = 0; s < MC; s++) f[s] = qlv + qsv * eps[(size_t)s * N_RAC + m];
    }

    // ---- EARLY: both supertiles' A rows (ILP across the K-chain) ----
    float4 a_m[2][2];
    #pragma unroll
    for (int st = 0; st < 2; st++) {
        int r = base_w + st * 32 + n31;
        if (r > N_REFLNS - 1) r = N_REFLNS - 1;
        const float4* mp = (const float4*)(metadata + (size_t)r * D_META + kh * 8);
        a_m[st][0] = mp[0];
        a_m[st][1] = mp[1];
    }

    // ---- weight fragments ----
    bf16x8 W1h, W1l;   // B[k][n], k=kh*8+j, n=n31
    {
        float tmp[8];
        #pragma unroll
        for (int j = 0; j < 8; j++) tmp[j] = W1[(kh * 8 + j) * HIDDEN + n31];
        split_hilo(tmp, W1h, W1l);
    }
    float b1v = b1[n31];
    bf16x8 W2h, W2l;   // B[k][n], k=q*8+j, n=c16
    {
        float tmp[8];
        #pragma unroll
        for (int j = 0; j < 8; j++) tmp[j] = (c16 < MC) ? W2[(q * 8 + j) * MC + c16] : 0.0f;
        split_hilo(tmp, W2h, W2l);
    }
    float b2v = (c16 < MC) ? b2[c16] : 0.0f;

    float* Hb = &sH[wave][0];
    float* Lb = &sL[wave][0];

    #pragma unroll
    for (int st = 0; st < 2; st++) {
        // ---- A-frag split ----
        float4 a0 = a_m[st][0], a1 = a_m[st][1];
        float av[8] = {a0.x, a0.y, a0.z, a0.w, a1.x, a1.y, a1.z, a1.w};
        bf16x8 Ah, Al;
        split_hilo(av, Ah, Al);

        // ---- layer 1: one 32x32 tile, 3-term hi/lo ----
        f32x16 cc;
        #pragma unroll
        for (int i = 0; i < 16; i++) cc[i] = b1v;
        cc = MFMA32(Al, W1h, cc);
        cc = MFMA32(Ah, W1l, cc);
        cc = MFMA32(Ah, W1h, cc);
        #pragma unroll
        for (int i = 0; i < 16; i++) {
            int row = (i & 3) + 8 * (i >> 2) + 4 * kh;
            Hb[row * 36 + n31] = fmaxf(cc[i], 0.0f);
        }

        // ---- layer 2: two 16-row tiles (same-wave LDS ordering) ----
        #pragma unroll
        for (int t2 = 0; t2 < 2; t2++) {
            const float4* hp = (const float4*)(Hb + (t2 * 16 + c16) * 36 + q * 8);
            bf16x8 Hh = pack8_rne(hp[0], hp[1]);
            f32x4 c2 = {b2v, b2v, b2v, b2v};
            c2 = MFMA16(Hh, W2l, c2);
            c2 = MFMA16(Hh, W2h, c2);
            if (c16 < MC) {
                #pragma unroll
                for (int rr = 0; rr < 4; rr++) {
                    Lb[(st * 2 + t2) * 160 + (q * 4 + rr) * 10 + c16] = c2[rr];
                }
            }
        }
    }

    // ---- epilogue: one reflection per lane ----
    float ll_sum = 0.0f;
    {
        float lg[MC];
        const float2* lp = (const float2*)(Lb + (lane >> 4) * 160 + c16 * 10);
        float2 p0 = lp[0], p1 = lp[1], p2 = lp[2], p3 = lp[3];
        lg[0] = p0.x; lg[1] = p0.y; lg[2] = p1.x; lg[3] = p1.y;
        lg[4] = p2.x; lg[5] = p2.y; lg[6] = p3.x; lg[7] = p3.y;

        float sum_ip = 0.0f, sum_d2 = 0.0f;
        #pragma unroll
        for (int s = 0; s < MC; s++) {
            float sc = softplus_fast(lg[s]);
            float ip = f[s] * f[s] * sc;
            sum_ip += ip;
            float d = ip - io;
            sum_d2 = fmaf(d, d, sum_d2);
        }
        float inv = __builtin_amdgcn_rcpf(sg);
        if (valid) out_ipred[n] = sum_ip * (1.0f / MC);
        ll_sum = -0.5f * sum_d2 * inv * inv
                 - (float)MC * (0.5f * LOG_2PI)
                 - (float)MC * (LN2 * __builtin_amdgcn_logf(sg));
    }

    // ---- wave-level segmented inclusive scan over sorted image ids ----
    float v = valid ? ll_sum : 0.0f;
    float c = valid ? 1.0f : 0.0f;
    int   id = img;
    #pragma unroll
    for (int d = 1; d < 64; d <<= 1) {
        float pv = __shfl_up(v, d, 64);
        float pc = __shfl_up(c, d, 64);
        int  pid = __shfl_up(id, d, 64);
        if (lane >= d && pid == id) { v += pv; c += pc; }
    }
    int nid = __shfl_down(id, 1, 64);
    bool tail = (lane == 63) || (nid != id);
    if (valid && tail && c > 0.0f) {
        atomicAdd(&img_sum[id], v);
        atomicAdd(&img_cnt[id], c);
    }
}

// ---------------- Kernel C: finalize scalars ----------------
__global__ __launch_bounds__(256) void k_final(
    const float* __restrict__ img_sum,
    const float* __restrict__ img_cnt,
    const float* __restrict__ kl_sum,
    float* __restrict__ out)
{
    __shared__ float sred[256];
    float acc = 0.0f;
    for (int i = threadIdx.x; i < N_IMAGES; i += 256) {
        acc += img_sum[i] / fmaxf(img_cnt[i], 1.0f);
    }
    sred[threadIdx.x] = acc;
    __syncthreads();
    #pragma unroll
    for (int s = 128; s > 0; s >>= 1) {
        if (threadIdx.x < s) sred[threadIdx.x] += sred[threadIdx.x + s];
        __syncthreads();
    }
    if (threadIdx.x == 0) {
        float mean_ll = sred[0] / ((float)MC * (float)N_IMAGES);
        out[N_REFLNS]     = -mean_ll;
        out[N_REFLNS + 1] = kl_sum[0] * (1.0f / (float)N_RAC);
    }
}

extern "C" void kernel_launch(void* const* d_in, const int* in_sizes, int n_in,
                              void* d_out, int out_size, void* d_ws, size_t ws_size,
                              hipStream_t stream) {
    const float* q_loc       = (const float*)d_in[0];
    const float* q_log_scale = (const float*)d_in[1];
    const float* eps         = (const float*)d_in[2];
    const float* metadata    = (const float*)d_in[3];
    const float* W1          = (const float*)d_in[4];
    const float* b1          = (const float*)d_in[5];
    const float* W2          = (const float*)d_in[6];
    const float* b2          = (const float*)d_in[7];
    const float* iobs        = (const float*)d_in[8];
    const float* sigiobs     = (const float*)d_in[9];
    const int*   image_id    = (const int*)d_in[10];
    const int*   miller_id   = (const int*)d_in[11];
    float* out = (float*)d_out;

    char* ws = (char*)d_ws;
    float* img_sum = (float*)ws;                 // 8192
    float* img_cnt = img_sum + N_IMAGES;         // 8192
    float* kl_sum  = img_cnt + N_IMAGES;         // 1
    const size_t z_off = 65664;
    bool has_z = (ws_size >= z_off + (size_t)N_RAC * MC * sizeof(float));
    float* zT = has_z ? (float*)(ws + z_off) : nullptr;

    hipMemsetAsync(d_ws, 0, (2 * N_IMAGES + 1) * sizeof(float), stream);

    k_z_kl<<<(N_RAC / 4 + 255) / 256, 256, 0, stream>>>(q_loc, q_log_scale, eps, zT, kl_sum);

    if (has_z) {
        k_main<true><<<(N_REFLNS + 255) / 256, 256, 0, stream>>>(
            metadata, W1, b1, W2, b2, iobs, sigiobs, image_id, miller_id,
            zT, q_loc, q_log_scale, eps, out, img_sum, img_cnt);
    } else {
        k_main<false><<<(N_REFLNS + 255) / 256, 256, 0, stream>>>(
            metadata, W1, b1, W2, b2, iobs, sigiobs, image_id, miller_id,
            nullptr, q_loc, q_log_scale, eps, out, img_sum, img_cnt);
    }

    k_final<<<1, 256, 0, stream>>>(img_sum, img_cnt, kl_sum, out);
}